// Round 1
// baseline (128.829 us; speedup 1.0000x reference)
//
#include <hip/hip_runtime.h>
#include <hip/hip_bf16.h>

// Problem constants (fixed by reference)
#define B_   64
#define N_   512
#define K_   16
#define D_   128   // WORD == EMB == 128
#define NPB  8     // nodes per block

// ---------------------------------------------------------------------------
// Kernel A: base = word_embs @ enc_w1 + agg(lib_embs, neibors_lib) @ weight
//           t1   = tanh(base)
// One block handles NPB consecutive nodes of one batch. 128 threads = e-dim.
// ---------------------------------------------------------------------------
__global__ __launch_bounds__(128) void kA(const float* __restrict__ word,
                                          const int* __restrict__ nbrL,
                                          const float* __restrict__ lib,
                                          const float* __restrict__ weight,
                                          const float* __restrict__ enc1,
                                          float* __restrict__ base,
                                          float* __restrict__ t1) {
    __shared__ float sw[NPB][D_];  // word rows
    __shared__ float sa[NPB][D_];  // aggregated lib rows
    const int t  = threadIdx.x;
    const int blk = blockIdx.x;            // 0..4095
    const int b  = blk >> 6;               // / (N_/NPB)
    const int n0 = (blk & 63) * NPB;

    const float* wordB = word + ((size_t)b * N_ + n0) * D_;
    const int*   idxB  = nbrL + ((size_t)b * N_ + n0) * K_;
    const float* libB  = lib  + (size_t)b * N_ * D_;

#pragma unroll
    for (int i = 0; i < NPB; ++i) {
        sw[i][t] = wordB[i * D_ + t];
        float s = 0.f;
#pragma unroll
        for (int k = 0; k < K_; ++k) {
            int idx = idxB[i * K_ + k];
            s += libB[(size_t)idx * D_ + t];
        }
        sa[i][t] = s * (1.0f / K_);
    }
    __syncthreads();

    float acc[NPB];
#pragma unroll
    for (int i = 0; i < NPB; ++i) acc[i] = 0.f;

    for (int w4 = 0; w4 < D_; w4 += 4) {
        // weights for this thread's e-column, 4 consecutive w's
        float e0 = enc1[(w4 + 0) * D_ + t];
        float e1 = enc1[(w4 + 1) * D_ + t];
        float e2 = enc1[(w4 + 2) * D_ + t];
        float e3 = enc1[(w4 + 3) * D_ + t];
        float q0 = weight[(w4 + 0) * D_ + t];
        float q1 = weight[(w4 + 1) * D_ + t];
        float q2 = weight[(w4 + 2) * D_ + t];
        float q3 = weight[(w4 + 3) * D_ + t];
#pragma unroll
        for (int i = 0; i < NPB; ++i) {
            float4 xs = *(const float4*)&sw[i][w4];
            float4 xa = *(const float4*)&sa[i][w4];
            acc[i] += xs.x * e0 + xs.y * e1 + xs.z * e2 + xs.w * e3
                    + xa.x * q0 + xa.y * q1 + xa.z * q2 + xa.w * q3;
        }
    }

#pragma unroll
    for (int i = 0; i < NPB; ++i) {
        size_t o = ((size_t)b * N_ + n0 + i) * D_ + t;
        float v = acc[i];
        base[o] = v;
        t1[o]   = tanhf(v);
    }
}

// ---------------------------------------------------------------------------
// Kernel B: t2 = tanh(base + agg(t1, neibors) @ enc_w2)
//           pooled[b][e] += sum_n mask[b][n] * t2[b][n][e]
// ---------------------------------------------------------------------------
__global__ __launch_bounds__(128) void kB(const float* __restrict__ t1,
                                          const int* __restrict__ nbr,
                                          const float* __restrict__ enc2,
                                          const float* __restrict__ base,
                                          const float* __restrict__ mask,
                                          float* __restrict__ pooled) {
    __shared__ float sa[NPB][D_];
    const int t  = threadIdx.x;
    const int blk = blockIdx.x;
    const int b  = blk >> 6;
    const int n0 = (blk & 63) * NPB;

    const int*   idxB = nbr + ((size_t)b * N_ + n0) * K_;
    const float* t1B  = t1 + (size_t)b * N_ * D_;

#pragma unroll
    for (int i = 0; i < NPB; ++i) {
        float s = 0.f;
#pragma unroll
        for (int k = 0; k < K_; ++k) {
            int idx = idxB[i * K_ + k];
            s += t1B[(size_t)idx * D_ + t];
        }
        sa[i][t] = s * (1.0f / K_);
    }
    __syncthreads();

    float acc[NPB];
#pragma unroll
    for (int i = 0; i < NPB; ++i) acc[i] = 0.f;

    for (int w4 = 0; w4 < D_; w4 += 4) {
        float e0 = enc2[(w4 + 0) * D_ + t];
        float e1 = enc2[(w4 + 1) * D_ + t];
        float e2 = enc2[(w4 + 2) * D_ + t];
        float e3 = enc2[(w4 + 3) * D_ + t];
#pragma unroll
        for (int i = 0; i < NPB; ++i) {
            float4 xa = *(const float4*)&sa[i][w4];
            acc[i] += xa.x * e0 + xa.y * e1 + xa.z * e2 + xa.w * e3;
        }
    }

    float pacc = 0.f;
#pragma unroll
    for (int i = 0; i < NPB; ++i) {
        size_t o = ((size_t)b * N_ + n0 + i) * D_ + t;
        float v = tanhf(base[o] + acc[i]);
        pacc += v * mask[(size_t)b * N_ + n0 + i];
    }
    atomicAdd(&pooled[b * D_ + t], pacc);
}

// ---------------------------------------------------------------------------
// Kernel C: out = pooled @ weight2   (64 x 128 @ 128 x 128)
// ---------------------------------------------------------------------------
__global__ __launch_bounds__(128) void kC(const float* __restrict__ pooled,
                                          const float* __restrict__ w2,
                                          float* __restrict__ out) {
    const int b = blockIdx.x;
    const int t = threadIdx.x;
    __shared__ float p[D_];
    p[t] = pooled[b * D_ + t];
    __syncthreads();
    float acc = 0.f;
#pragma unroll 4
    for (int f = 0; f < D_; ++f) acc += p[f] * w2[f * D_ + t];
    out[b * D_ + t] = acc;
}

extern "C" void kernel_launch(void* const* d_in, const int* in_sizes, int n_in,
                              void* d_out, int out_size, void* d_ws, size_t ws_size,
                              hipStream_t stream) {
    const float* word_embs  = (const float*)d_in[0];
    const int*   neibors    = (const int*)d_in[1];
    const float* lib_embs   = (const float*)d_in[2];
    const int*   neibors_lib= (const int*)d_in[3];
    const float* mask       = (const float*)d_in[4];
    const float* weight     = (const float*)d_in[5];
    const float* weight2    = (const float*)d_in[6];
    const float* enc_w1     = (const float*)d_in[7];
    const float* enc_w2     = (const float*)d_in[8];
    float* out = (float*)d_out;

    char* ws = (char*)d_ws;
    float* base   = (float*)(ws);                                   // 16 MB
    float* t1     = (float*)(ws + (size_t)B_ * N_ * D_ * 4);        // 16 MB
    float* pooled = (float*)(ws + 2 * (size_t)B_ * N_ * D_ * 4);    // 32 KB

    hipMemsetAsync(pooled, 0, B_ * D_ * sizeof(float), stream);

    const int nblk = (B_ * N_) / NPB;  // 4096
    kA<<<nblk, 128, 0, stream>>>(word_embs, neibors_lib, lib_embs, weight, enc_w1, base, t1);
    kB<<<nblk, 128, 0, stream>>>(t1, neibors, enc_w2, base, mask, pooled);
    kC<<<B_, 128, 0, stream>>>(pooled, weight2, out);
}